// Round 1
// baseline (448.433 us; speedup 1.0000x reference)
//
#include <hip/hip_runtime.h>
#include <hip/hip_bf16.h>
#include <cstdint>

// ---------------- problem constants (fixed by harness) ----------------
constexpr int CBATCH = 32;    // B
constexpr int CT = 800;       // T frames
constexpr int CD = 512;       // eprojs (K)
constexpr int CV = 1024;      // odim (N)
constexpr int CL = 100;       // max label len
constexpr int CM = CBATCH * CT;   // 25600 GEMM rows
constexpr int CS = 2 * CL + 1;    // 201 extended states
constexpr int CSP = 204;          // padded state count (51 lanes * 4)
constexpr float NEGV = -1e30f;

typedef __bf16 bf16x8 __attribute__((ext_vector_type(8)));
typedef float f32x4 __attribute__((ext_vector_type(4)));

// ---------------- helpers ----------------
__device__ inline unsigned short f2bf(float f) {
  union { float f; unsigned u; } v; v.f = f;
  unsigned u = v.u;
  unsigned r = (u + 0x7fffu + ((u >> 16) & 1u)) >> 16;
  return (unsigned short)r;
}

__device__ inline float lae(float x, float y) {
  float m = fmaxf(x, y);
  float d = fminf(x, y) - m;           // <= 0
  return m + __logf(1.0f + __expf(d));
}

// ---------------- 1. fp32 -> bf16 convert ----------------
__global__ void cvt_kernel(const float* __restrict__ in, unsigned short* __restrict__ out, int n4) {
  int i = blockIdx.x * blockDim.x + threadIdx.x;
  if (i < n4) {
    float4 v = reinterpret_cast<const float4*>(in)[i];
    ushort4 o;
    o.x = f2bf(v.x); o.y = f2bf(v.y); o.z = f2bf(v.z); o.w = f2bf(v.w);
    reinterpret_cast<ushort4*>(out)[i] = o;
  }
}

// ---------------- 2. bf16 MFMA GEMM: C[M,V] = A[M,D] * Bt[V,D]^T + bias ----------------
constexpr int GBK = 64;    // K-tile
constexpr int LDSS = 72;   // padded LDS row stride (elements, 144B: 16B-aligned, conflict-benign)

__global__ __launch_bounds__(256, 2) void gemm_kernel(
    const unsigned short* __restrict__ A,   // [CM, CD] bf16 bits
    const unsigned short* __restrict__ Bt,  // [CV, CD] bf16 bits
    const float* __restrict__ bias,         // [CV]
    float* __restrict__ C)                  // [CM, CV] fp32
{
  __shared__ __align__(16) unsigned short As[128 * LDSS];
  __shared__ __align__(16) unsigned short Bs[128 * LDSS];
  const int tid = threadIdx.x;
  const int lane = tid & 63;
  const int wave = tid >> 6;          // 4 waves, 2x2 of 64x64
  const int wr = wave >> 1, wc = wave & 1;
  const int bm = blockIdx.x, bn = blockIdx.y;

  f32x4 acc[4][4] = {};

  for (int k0 = 0; k0 < CD; k0 += GBK) {
    // stage A,B tiles: 128 rows x 64 k each; 1024 16B-chunks per tile, 4 per thread
#pragma unroll
    for (int i = 0; i < 4; ++i) {
      int c = tid + 256 * i;
      int row = c >> 3, col = (c & 7) * 8;
      *reinterpret_cast<bf16x8*>(&As[row * LDSS + col]) =
          *reinterpret_cast<const bf16x8*>(&A[(size_t)(bm * 128 + row) * CD + k0 + col]);
      *reinterpret_cast<bf16x8*>(&Bs[row * LDSS + col]) =
          *reinterpret_cast<const bf16x8*>(&Bt[(size_t)(bn * 128 + row) * CD + k0 + col]);
    }
    __syncthreads();
#pragma unroll
    for (int kk = 0; kk < 2; ++kk) {
      bf16x8 af[4], bf[4];
#pragma unroll
      for (int m = 0; m < 4; ++m)
        af[m] = *reinterpret_cast<const bf16x8*>(
            &As[(wr * 64 + m * 16 + (lane & 15)) * LDSS + kk * 32 + (lane >> 4) * 8]);
#pragma unroll
      for (int n = 0; n < 4; ++n)
        bf[n] = *reinterpret_cast<const bf16x8*>(
            &Bs[(wc * 64 + n * 16 + (lane & 15)) * LDSS + kk * 32 + (lane >> 4) * 8]);
#pragma unroll
      for (int m = 0; m < 4; ++m)
#pragma unroll
        for (int n = 0; n < 4; ++n)
          acc[m][n] = __builtin_amdgcn_mfma_f32_16x16x32_bf16(af[m], bf[n], acc[m][n], 0, 0, 0);
    }
    __syncthreads();
  }

  // epilogue: C layout col=lane&15, row=(lane>>4)*4+reg  [verified m89/m91]
  float bv[4];
#pragma unroll
  for (int n = 0; n < 4; ++n)
    bv[n] = bias[bn * 128 + wc * 64 + n * 16 + (lane & 15)];
#pragma unroll
  for (int m = 0; m < 4; ++m) {
    int rbase = bm * 128 + wr * 64 + m * 16 + (lane >> 4) * 4;
#pragma unroll
    for (int n = 0; n < 4; ++n) {
      int col = bn * 128 + wc * 64 + n * 16 + (lane & 15);
#pragma unroll
      for (int r = 0; r < 4; ++r)
        C[(size_t)(rbase + r) * CV + col] = acc[m][n][r] + bv[n];
    }
  }
}

// ---------------- 3. row log-sum-exp over V=1024, one wave per row ----------------
__global__ void lse_kernel(const float* __restrict__ C, float* __restrict__ lse) {
  const int wave = threadIdx.x >> 6, lane = threadIdx.x & 63;
  const int row = blockIdx.x * 4 + wave;
  const float* p = C + (size_t)row * CV;
  float4 v[4];
#pragma unroll
  for (int i = 0; i < 4; ++i) v[i] = reinterpret_cast<const float4*>(p)[lane + 64 * i];
  float m = v[0].x;
#pragma unroll
  for (int i = 0; i < 4; ++i) {
    m = fmaxf(m, v[i].x); m = fmaxf(m, v[i].y);
    m = fmaxf(m, v[i].z); m = fmaxf(m, v[i].w);
  }
#pragma unroll
  for (int off = 32; off >= 1; off >>= 1) m = fmaxf(m, __shfl_xor(m, off));
  float s = 0.f;
#pragma unroll
  for (int i = 0; i < 4; ++i) {
    s += __expf(v[i].x - m); s += __expf(v[i].y - m);
    s += __expf(v[i].z - m); s += __expf(v[i].w - m);
  }
#pragma unroll
  for (int off = 32; off >= 1; off >>= 1) s += __shfl_xor(s, off);
  if (lane == 0) lse[row] = m + __logf(s);
}

// ---------------- 4. gather log-probs at extended-label indices ----------------
__global__ void gather_kernel(const float* __restrict__ C, const float* __restrict__ lse,
                              const int* __restrict__ labels, float* __restrict__ lpg) {
  const int bt = blockIdx.x;         // b*CT + t
  const int b = bt / CT;
  const int lane = threadIdx.x;
  if (lane >= CSP / 4) return;       // 51 active lanes
  const float l = lse[bt];
  const float* row = C + (size_t)bt * CV;
  const int* lab = labels + b * CL;
  const int s0 = lane * 4;
  float vals[4];
#pragma unroll
  for (int j = 0; j < 4; ++j) {
    int s = s0 + j;
    if (s >= CS) { vals[j] = NEGV; continue; }
    int e = (s & 1) ? lab[s >> 1] : 0;
    vals[j] = row[e] - l;
  }
  float4 o; o.x = vals[0]; o.y = vals[1]; o.z = vals[2]; o.w = vals[3];
  reinterpret_cast<float4*>(lpg + (size_t)bt * CSP)[lane] = o;
}

// ---------------- 5. CTC alpha recursion: one wave per batch element ----------------
__global__ void ctc_kernel(const float* __restrict__ lpg, const int* __restrict__ labels,
                           const int* __restrict__ ilens, const int* __restrict__ llens,
                           float* __restrict__ out) {
  const int b = blockIdx.x;
  const int lane = threadIdx.x;
  const int ilen = ilens[b];
  const int ll = llens[b];
  const int* lab = labels + b * CL;
  const int s0 = lane * 4;

  bool valid[4], allow[4];
#pragma unroll
  for (int j = 0; j < 4; ++j) {
    int s = s0 + j;
    valid[j] = (s < CS);
    allow[j] = false;
    if (valid[j] && (s & 1) && s >= 3) {
      int idx = s >> 1;                       // 1..99 for s in [3,199]
      allow[j] = (lab[idx] != lab[idx - 1]);  // skip allowed iff labels differ
    }
  }

  const float* base = lpg + (size_t)b * CT * CSP;
  float a[4] = {NEGV, NEGV, NEGV, NEGV};
  if (lane == 0) {
    float4 r0 = *reinterpret_cast<const float4*>(base);
    a[0] = r0.x;
    a[1] = (ll > 0) ? r0.y : NEGV;
  }

  auto loadrow = [&](int t) -> float4 {
    if (lane < CSP / 4) return reinterpret_cast<const float4*>(base + (size_t)t * CSP)[lane];
    float4 z; z.x = z.y = z.z = z.w = NEGV; return z;
  };
  float4 f1 = loadrow(1);
  float4 f2 = loadrow(2);

  for (int t = 1; t < CT; ++t) {
    float4 lp = f1; f1 = f2;
    if (t + 2 < CT) f2 = loadrow(t + 2);
    float na3 = __shfl_up(a[3], 1);
    float na2 = __shfl_up(a[2], 1);
    if (lane == 0) { na3 = NEGV; na2 = NEGV; }
    float p1[4] = {na3, a[0], a[1], a[2]};
    float p2[4] = {na2, na3, a[0], a[1]};
    float lpv[4] = {lp.x, lp.y, lp.z, lp.w};
    const bool active = (t < ilen);
#pragma unroll
    for (int j = 0; j < 4; ++j) {
      float c = lae(a[j], p1[j]);
      if (allow[j]) c = lae(c, p2[j]);
      float nv = c + lpv[j];
      if (active && valid[j]) a[j] = nv;
    }
  }

  __shared__ float sal[CSP];
  if (lane < CSP / 4) {
#pragma unroll
    for (int j = 0; j < 4; ++j) sal[s0 + j] = a[j];
  }
  __syncthreads();
  if (lane == 0) {
    float last = sal[2 * ll];
    float prev = (ll > 0) ? sal[2 * ll - 1] : NEGV;
    float v = lae(last, prev);
    atomicAdd(out, -v * (1.0f / CBATCH));
  }
}

// ---------------- launch ----------------
extern "C" void kernel_launch(void* const* d_in, const int* in_sizes, int n_in,
                              void* d_out, int out_size, void* d_ws, size_t ws_size,
                              hipStream_t stream) {
  const float* hpad = (const float*)d_in[0];
  const float* W    = (const float*)d_in[1];
  const float* bias = (const float*)d_in[2];
  const int* labels = (const int*)d_in[3];
  const int* ilens  = (const int*)d_in[4];
  const int* llens  = (const int*)d_in[5];
  float* out = (float*)d_out;

  char* ws = (char*)d_ws;
  size_t off = 0;
  auto alloc = [&](size_t bytes) -> void* {
    void* p = ws + off;
    off = (off + bytes + 255) & ~(size_t)255;
    return p;
  };
  unsigned short* Abf = (unsigned short*)alloc((size_t)CM * CD * 2);  // 26.2 MB
  unsigned short* Wbf = (unsigned short*)alloc((size_t)CV * CD * 2);  //  1.0 MB
  float* logits = (float*)alloc((size_t)CM * CV * 4);                 // 104.9 MB
  float* lse    = (float*)alloc((size_t)CM * 4);                      //  0.1 MB
  float* lpg    = (float*)alloc((size_t)CM * CSP * 4);                // 20.9 MB

  hipMemsetAsync(d_out, 0, sizeof(float), stream);

  cvt_kernel<<<(CM * CD / 4 + 255) / 256, 256, 0, stream>>>(hpad, Abf, CM * CD / 4);
  cvt_kernel<<<(CV * CD / 4 + 255) / 256, 256, 0, stream>>>(W, Wbf, CV * CD / 4);
  gemm_kernel<<<dim3(CM / 128, CV / 128), 256, 0, stream>>>(Abf, Wbf, bias, logits);
  lse_kernel<<<CM / 4, 256, 0, stream>>>(logits, lse);
  gather_kernel<<<CM, 64, 0, stream>>>(logits, lse, labels, lpg);
  ctc_kernel<<<CBATCH, 64, 0, stream>>>(lpg, labels, ilens, llens, out);
}

// Round 2
// 195.650 us; speedup vs baseline: 2.2920x; 2.2920x over previous
//
#include <hip/hip_runtime.h>
#include <hip/hip_bf16.h>
#include <cstdint>

// ---------------- problem constants (fixed by harness) ----------------
constexpr int CBATCH = 32;    // B
constexpr int CT = 800;       // T frames
constexpr int CD = 512;       // eprojs (K)
constexpr int CV = 1024;      // odim (N)
constexpr int CL = 100;       // max label len
constexpr int CM = CBATCH * CT;   // 25600 GEMM rows
constexpr int CS = 2 * CL + 1;    // 201 extended states
constexpr int CSP = 204;          // padded state count (51 lanes * 4)
constexpr float NEGV = -1e30f;
constexpr float INV_LN2 = 1.4426950408889634f;
constexpr float LN2F = 0.6931471805599453f;

typedef __bf16 bf16x8 __attribute__((ext_vector_type(8)));
typedef float f32x4 __attribute__((ext_vector_type(4)));

// ---------------- helpers ----------------
__device__ inline unsigned short f2bf(float f) {
  union { float f; unsigned u; } v; v.f = f;
  unsigned u = v.u;
  unsigned r = (u + 0x7fffu + ((u >> 16) & 1u)) >> 16;
  return (unsigned short)r;
}

__device__ inline float fexp2(float x) {
#if __has_builtin(__builtin_amdgcn_exp2f)
  return __builtin_amdgcn_exp2f(x);
#else
  return __expf(x * LN2F);
#endif
}
__device__ inline float flog2(float x) {
#if __has_builtin(__builtin_amdgcn_logf)
  return __builtin_amdgcn_logf(x);   // v_log_f32 is log2
#else
  return __logf(x) * INV_LN2;
#endif
}

// log2-domain logaddexp: log2(2^x + 2^y)
__device__ inline float lae2_2(float x, float y) {
  float m = fmaxf(x, y);
  float d = fminf(x, y) - m;           // <= 0
  return m + flog2(1.0f + fexp2(d));
}
// 3-way: log2(2^x + 2^y + 2^z)
__device__ inline float lae2_3(float x, float y, float z) {
  float m = fmaxf(fmaxf(x, y), z);     // v_max3
  float s = fexp2(x - m) + fexp2(y - m) + fexp2(z - m);
  return m + flog2(s);
}

// wave_shr:1 — lane i gets lane i-1's value; lane 0 gets `fill`. Pure VALU (DPP).
__device__ inline float dpp_shr1(float x, float fill) {
  int xi = __builtin_bit_cast(int, x);
  int fi = __builtin_bit_cast(int, fill);
  int r = __builtin_amdgcn_update_dpp(fi, xi, 0x138, 0xF, 0xF, false);
  return __builtin_bit_cast(float, r);
}

// ---------------- 1. fp32 -> bf16 convert ----------------
__global__ void cvt_kernel(const float* __restrict__ in, unsigned short* __restrict__ out, int n4) {
  int i = blockIdx.x * blockDim.x + threadIdx.x;
  if (i < n4) {
    float4 v = reinterpret_cast<const float4*>(in)[i];
    ushort4 o;
    o.x = f2bf(v.x); o.y = f2bf(v.y); o.z = f2bf(v.z); o.w = f2bf(v.w);
    reinterpret_cast<ushort4*>(out)[i] = o;
  }
}

// ---------------- 2. bf16 MFMA GEMM: C[M,V] = A[M,D] * Bt[V,D]^T + bias ----------------
// m97 structure: linear [128][64] LDS tiles staged via global_load_lds width=16.
constexpr int GBK = 64;    // K-tile

__device__ inline void gload_lds16(const void* g, void* l) {
  __builtin_amdgcn_global_load_lds(
      (const __attribute__((address_space(1))) unsigned int*)g,
      (__attribute__((address_space(3))) unsigned int*)l, 16, 0, 0);
}

__global__ __launch_bounds__(256, 2) void gemm_kernel(
    const unsigned short* __restrict__ A,   // [CM, CD] bf16 bits
    const unsigned short* __restrict__ Bt,  // [CV, CD] bf16 bits
    const float* __restrict__ bias,         // [CV]
    float* __restrict__ C)                  // [CM, CV] fp32
{
  __shared__ __align__(16) unsigned short As[128 * GBK];  // 16 KB, linear
  __shared__ __align__(16) unsigned short Bs[128 * GBK];
  const int tid = threadIdx.x;
  const int lane = tid & 63;
  const int wave = tid >> 6;          // 4 waves, 2x2 of 64x64
  const int wr = wave >> 1, wc = wave & 1;
  const int bm = blockIdx.x, bn = blockIdx.y;

  f32x4 acc[4][4] = {};

  for (int k0 = 0; k0 < CD; k0 += GBK) {
    // stage A,B tiles: 1024 16B-chunks per tile, 4 per thread.
    // chunk c -> LDS byte c*16 == row-major [128][64]; per-wave dest is
    // wave-uniform base + lane*16 (linear, as global_load_lds requires).
#pragma unroll
    for (int i = 0; i < 4; ++i) {
      int c = tid + 256 * i;
      int row = c >> 3, col = (c & 7) * 8;
      gload_lds16(&A[(size_t)(bm * 128 + row) * CD + k0 + col], &As[c * 8]);
      gload_lds16(&Bt[(size_t)(bn * 128 + row) * CD + k0 + col], &Bs[c * 8]);
    }
    __syncthreads();   // compiler drains vmcnt before s_barrier
#pragma unroll
    for (int kk = 0; kk < 2; ++kk) {
      bf16x8 af[4], bfr[4];
#pragma unroll
      for (int m = 0; m < 4; ++m)
        af[m] = *reinterpret_cast<const bf16x8*>(
            &As[(wr * 64 + m * 16 + (lane & 15)) * GBK + kk * 32 + (lane >> 4) * 8]);
#pragma unroll
      for (int n = 0; n < 4; ++n)
        bfr[n] = *reinterpret_cast<const bf16x8*>(
            &Bs[(wc * 64 + n * 16 + (lane & 15)) * GBK + kk * 32 + (lane >> 4) * 8]);
#pragma unroll
      for (int m = 0; m < 4; ++m)
#pragma unroll
        for (int n = 0; n < 4; ++n)
          acc[m][n] = __builtin_amdgcn_mfma_f32_16x16x32_bf16(af[m], bfr[n], acc[m][n], 0, 0, 0);
    }
    __syncthreads();
  }

  // epilogue: C layout col=lane&15, row=(lane>>4)*4+reg  [verified m89/m91]
  float bv[4];
#pragma unroll
  for (int n = 0; n < 4; ++n)
    bv[n] = bias[bn * 128 + wc * 64 + n * 16 + (lane & 15)];
#pragma unroll
  for (int m = 0; m < 4; ++m) {
    int rbase = bm * 128 + wr * 64 + m * 16 + (lane >> 4) * 4;
#pragma unroll
    for (int n = 0; n < 4; ++n) {
      int col = bn * 128 + wc * 64 + n * 16 + (lane & 15);
#pragma unroll
      for (int r = 0; r < 4; ++r)
        C[(size_t)(rbase + r) * CV + col] = acc[m][n][r] + bv[n];
    }
  }
}

// ---------------- 3. fused row log-sum-exp + extended-label gather ----------------
// one wave per (b,t) row; lp output pre-scaled to log2 domain.
__global__ void lse_gather_kernel(const float* __restrict__ C, const int* __restrict__ labels,
                                  float* __restrict__ lpg) {
  const int wave = threadIdx.x >> 6, lane = threadIdx.x & 63;
  const int row = blockIdx.x * 4 + wave;   // bt
  const int b = row / CT;
  const float* p = C + (size_t)row * CV;
  float4 v[4];
#pragma unroll
  for (int i = 0; i < 4; ++i) v[i] = reinterpret_cast<const float4*>(p)[lane + 64 * i];
  float m = v[0].x;
#pragma unroll
  for (int i = 0; i < 4; ++i) {
    m = fmaxf(m, v[i].x); m = fmaxf(m, v[i].y);
    m = fmaxf(m, v[i].z); m = fmaxf(m, v[i].w);
  }
#pragma unroll
  for (int off = 32; off >= 1; off >>= 1) m = fmaxf(m, __shfl_xor(m, off));
  float s = 0.f;
#pragma unroll
  for (int i = 0; i < 4; ++i) {
    s += __expf(v[i].x - m); s += __expf(v[i].y - m);
    s += __expf(v[i].z - m); s += __expf(v[i].w - m);
  }
#pragma unroll
  for (int off = 32; off >= 1; off >>= 1) s += __shfl_xor(s, off);
  const float l = m + __logf(s);           // natural-log lse, all lanes have it

  if (lane < CSP / 4) {                    // 51 active lanes gather
    const int* lab = labels + b * CL;
    const int s0 = lane * 4;
    float vals[4];
#pragma unroll
    for (int j = 0; j < 4; ++j) {
      int st = s0 + j;
      if (st >= CS) { vals[j] = NEGV; continue; }
      int e = (st & 1) ? lab[st >> 1] : 0;
      vals[j] = (p[e] - l) * INV_LN2;      // log2 domain
    }
    float4 o; o.x = vals[0]; o.y = vals[1]; o.z = vals[2]; o.w = vals[3];
    reinterpret_cast<float4*>(lpg + (size_t)row * CSP)[lane] = o;
  }
}

// ---------------- 4. CTC alpha recursion (log2 domain): one wave per batch ----------------
__global__ void ctc_kernel(const float* __restrict__ lpg, const int* __restrict__ labels,
                           const int* __restrict__ ilens, const int* __restrict__ llens,
                           float* __restrict__ out) {
  const int b = blockIdx.x;
  const int lane = threadIdx.x;
  const int ilen = ilens[b];
  const int ll = llens[b];
  const int* lab = labels + b * CL;
  const int s0 = lane * 4;

  // skip-transition allow flags: only odd states (j=1,3) can be allowed
  bool al1 = false, al3 = false;
  if (lane < CSP / 4) {
    int s1 = s0 + 1;
    if (s1 >= 3 && s1 < CS) al1 = (lab[s1 >> 1] != lab[(s1 >> 1) - 1]);
    int s3 = s0 + 3;
    if (s3 < CS) al3 = (lab[s3 >> 1] != lab[(s3 >> 1) - 1]);
  }

  const float* base = lpg + (size_t)b * CT * CSP;

  // init from t=0 row (log2 domain). Unguarded 64-lane loads overrun the
  // 816B row into the next row / pad — harmless, values discarded.
  float4 r0 = reinterpret_cast<const float4*>(base)[lane];
  float a[4];
  a[0] = (lane == 0) ? r0.x : NEGV;
  a[1] = (lane == 0 && ll > 0) ? r0.y : NEGV;
  a[2] = NEGV; a[3] = NEGV;

  // 16-deep register prefetch ring; pf[u] holds row (tb+u) at group start
  float4 pf[16];
#pragma unroll
  for (int u = 0; u < 16; ++u)
    pf[u] = reinterpret_cast<const float4*>(base + (size_t)(1 + u) * CSP)[lane];

  // t runs 1..800 exactly (50 groups of 16); t=800 update is masked off by
  // active=(t<ilen) since ilen<=800.
  for (int tb = 1; tb < CT + 1; tb += 16) {
#pragma unroll
    for (int u = 0; u < 16; ++u) {
      const int t = tb + u;
      float4 lp = pf[u];
      pf[u] = reinterpret_cast<const float4*>(base + (size_t)(t + 16) * CSP)[lane];
      float na3 = dpp_shr1(a[3], NEGV);          // state s0-1 from prev lane
      // j=0 (blank): paths {s, s-1}
      float c0 = lae2_2(a[0], na3);
      // j=1 (label): paths {s, s-1, s-2?}; s-1=a[0], s-2=na3
      float c1 = lae2_3(a[1], a[0], al1 ? na3 : NEGV);
      // j=2 (blank)
      float c2 = lae2_2(a[2], a[1]);
      // j=3 (label): s-1=a[2], s-2=a[1]
      float c3 = lae2_3(a[3], a[2], al3 ? a[1] : NEGV);
      if (t < ilen) {
        a[0] = c0 + lp.x; a[1] = c1 + lp.y;
        a[2] = c2 + lp.z; a[3] = c3 + lp.w;
      }
    }
  }

  __shared__ float sal[CSP];
  if (lane < CSP / 4) {
#pragma unroll
    for (int j = 0; j < 4; ++j) sal[s0 + j] = a[j];
  }
  __syncthreads();
  if (lane == 0) {
    float last = sal[2 * ll];
    float prev = (ll > 0) ? sal[2 * ll - 1] : NEGV;
    float v = lae2_2(last, prev);                // log2 domain
    atomicAdd(out, -v * (LN2F / CBATCH));        // back to natural log
  }
}

// ---------------- launch ----------------
extern "C" void kernel_launch(void* const* d_in, const int* in_sizes, int n_in,
                              void* d_out, int out_size, void* d_ws, size_t ws_size,
                              hipStream_t stream) {
  const float* hpad = (const float*)d_in[0];
  const float* W    = (const float*)d_in[1];
  const float* bias = (const float*)d_in[2];
  const int* labels = (const int*)d_in[3];
  const int* ilens  = (const int*)d_in[4];
  const int* llens  = (const int*)d_in[5];
  float* out = (float*)d_out;

  char* ws = (char*)d_ws;
  size_t off = 0;
  auto alloc = [&](size_t bytes) -> void* {
    void* p = ws + off;
    off = (off + bytes + 255) & ~(size_t)255;
    return p;
  };
  unsigned short* Abf = (unsigned short*)alloc((size_t)CM * CD * 2);        // 26.2 MB
  unsigned short* Wbf = (unsigned short*)alloc((size_t)CV * CD * 2);        //  1.0 MB
  float* logits = (float*)alloc((size_t)CM * CV * 4);                       // 104.9 MB
  float* lpg    = (float*)alloc((size_t)(CM + 64) * CSP * 4);               // 21.0 MB (+pad for prefetch overrun)

  hipMemsetAsync(d_out, 0, sizeof(float), stream);

  cvt_kernel<<<(CM * CD / 4 + 255) / 256, 256, 0, stream>>>(hpad, Abf, CM * CD / 4);
  cvt_kernel<<<(CV * CD / 4 + 255) / 256, 256, 0, stream>>>(W, Wbf, CV * CD / 4);
  gemm_kernel<<<dim3(CM / 128, CV / 128), 256, 0, stream>>>(Abf, Wbf, bias, logits);
  lse_gather_kernel<<<CM / 4, 256, 0, stream>>>(logits, labels, lpg);
  ctc_kernel<<<CBATCH, 64, 0, stream>>>(lpg, labels, ilens, llens, out);
}